// Round 1
// baseline (114.471 us; speedup 1.0000x reference)
//
#include <hip/hip_runtime.h>

// Problem constants (fixed by the reference).
constexpr int N = 4096;      // IN_FEATURES (reduction axis)
constexpr int F = 16384;     // OUT_DIM
constexpr int TPB = 256;     // threads per block
constexpr int XB = F / (TPB * 4);   // 16 blocks across columns (4 cols/thread)
constexpr int ROWS = 64;            // rows per chunk
constexpr int CHUNKS = N / ROWS;    // 64 row chunks

// SOBOL_RNG[i] == bitreverse8(gray(i)) for BITWIDTH=8 — closed form of the
// gray-code Sobol construction, verified against the reference generator.
__device__ __forceinline__ int sobol_thresh(int idx) {
    unsigned g = (unsigned)idx & 255u;   // rng_idx % 256 (matches Python % for int32)
    g ^= g >> 1;                         // gray code
    return (int)(__brev(g) >> 24);       // 8-bit bit reversal
}

// bit = rint((p+1)*128) > SOBOL[idx]   (jnp.round == round-half-even == rintf)
__device__ __forceinline__ int bitval(float p, int idx) {
    float s = rintf((p + 1.0f) * 128.0f);    // exact same single-rounding as jnp
    return s > (float)sobol_thresh(idx) ? 1 : 0;
}

// ---- Path A: exact int partials into workspace (no atomics) ----------------
__global__ __launch_bounds__(TPB) void count_partial(const float* __restrict__ prob,
                                                     const int* __restrict__ idx,
                                                     int* __restrict__ partial) {
    const int col4 = blockIdx.x * TPB + threadIdx.x;   // float4 index within a row
    const int row0 = blockIdx.y * ROWS;
    const float4* p4 = (const float4*)prob;
    const int4*   i4 = (const int4*)idx;
    size_t v = (size_t)row0 * (F / 4) + col4;

    int c0 = 0, c1 = 0, c2 = 0, c3 = 0;
#pragma unroll 4
    for (int r = 0; r < ROWS; ++r) {
        float4 p = p4[v];
        int4   q = i4[v];
        v += F / 4;
        c0 += bitval(p.x, q.x);
        c1 += bitval(p.y, q.y);
        c2 += bitval(p.z, q.z);
        c3 += bitval(p.w, q.w);
    }
    int4 c = make_int4(c0, c1, c2, c3);
    *(int4*)&partial[(size_t)blockIdx.y * F + (size_t)col4 * 4] = c;
}

__global__ __launch_bounds__(TPB) void finalize_partials(const int* __restrict__ partial,
                                                         const float* __restrict__ acc,
                                                         float* __restrict__ out) {
    const int f = blockIdx.x * TPB + threadIdx.x;
    int s = 0;
#pragma unroll 8
    for (int c = 0; c < CHUNKS; ++c) s += partial[(size_t)c * F + f];
    // same fp32 add + compare as the reference (rounding near 4096 matters)
    out[f] = (acc[f] + (float)s >= 4096.0f) ? 1.0f : 0.0f;
}

// ---- Path B (fallback if ws too small): float atomics into d_out -----------
__global__ __launch_bounds__(TPB) void zero_out(float* __restrict__ out) {
    out[blockIdx.x * TPB + threadIdx.x] = 0.0f;
}

__global__ __launch_bounds__(TPB) void count_atomic(const float* __restrict__ prob,
                                                    const int* __restrict__ idx,
                                                    float* __restrict__ out) {
    const int col4 = blockIdx.x * TPB + threadIdx.x;
    const int row0 = blockIdx.y * ROWS;
    const float4* p4 = (const float4*)prob;
    const int4*   i4 = (const int4*)idx;
    size_t v = (size_t)row0 * (F / 4) + col4;

    int c0 = 0, c1 = 0, c2 = 0, c3 = 0;
#pragma unroll 4
    for (int r = 0; r < ROWS; ++r) {
        float4 p = p4[v];
        int4   q = i4[v];
        v += F / 4;
        c0 += bitval(p.x, q.x);
        c1 += bitval(p.y, q.y);
        c2 += bitval(p.z, q.z);
        c3 += bitval(p.w, q.w);
    }
    // integer-valued float adds (<= 4096 each, 64 adders) are exact -> deterministic
    float* o = out + (size_t)col4 * 4;
    atomicAdd(o + 0, (float)c0);
    atomicAdd(o + 1, (float)c1);
    atomicAdd(o + 2, (float)c2);
    atomicAdd(o + 3, (float)c3);
}

__global__ __launch_bounds__(TPB) void finalize_inplace(const float* __restrict__ acc,
                                                        float* __restrict__ out) {
    const int f = blockIdx.x * TPB + threadIdx.x;
    out[f] = (acc[f] + out[f] >= 4096.0f) ? 1.0f : 0.0f;
}

extern "C" void kernel_launch(void* const* d_in, const int* in_sizes, int n_in,
                              void* d_out, int out_size, void* d_ws, size_t ws_size,
                              hipStream_t stream) {
    // setup_inputs order: st_in_prob[0], accumulator[1], input_bits[2] (UNUSED), rng_idx[3]
    const float* prob = (const float*)d_in[0];
    const float* acc  = (const float*)d_in[1];
    const int*   idx  = (const int*)d_in[3];
    float* out = (float*)d_out;

    const size_t need = (size_t)CHUNKS * F * sizeof(int);   // 4 MiB
    dim3 grid(XB, CHUNKS);
    if (ws_size >= need) {
        int* partial = (int*)d_ws;
        count_partial<<<grid, TPB, 0, stream>>>(prob, idx, partial);
        finalize_partials<<<F / TPB, TPB, 0, stream>>>(partial, acc, out);
    } else {
        zero_out<<<F / TPB, TPB, 0, stream>>>(out);
        count_atomic<<<grid, TPB, 0, stream>>>(prob, idx, out);
        finalize_inplace<<<F / TPB, TPB, 0, stream>>>(acc, out);
    }
}

// Round 2
// 109.904 us; speedup vs baseline: 1.0416x; 1.0416x over previous
//
#include <hip/hip_runtime.h>

// Problem constants (fixed by the reference).
constexpr int N = 4096;      // IN_FEATURES (reduction axis)
constexpr int F = 16384;     // OUT_DIM
constexpr int TPB = 256;     // threads per block
constexpr int XB = F / (TPB * 4);   // 16 blocks across columns (4 cols/thread)
constexpr int ROWS = 32;            // rows per chunk  (was 64)
constexpr int CHUNKS = N / ROWS;    // 128 row chunks -> 2048 blocks = 32 waves/CU demand

// SOBOL_RNG[i] == bitreverse8(gray(i)) for BITWIDTH=8 — closed form of the
// gray-code Sobol construction, verified against the reference generator.
__device__ __forceinline__ int sobol_thresh(int idx) {
    unsigned g = (unsigned)idx & 255u;   // rng_idx % 256
    g ^= g >> 1;                         // gray code
    return (int)(__brev(g) >> 24);       // 8-bit bit reversal
}

// bit = rint((p+1)*128) > SOBOL[idx]   (jnp.round == round-half-even == rintf)
__device__ __forceinline__ int bitval(float p, int idx) {
    float s = rintf(fmaf(p, 128.0f, 128.0f));   // single fma + rndne, exact
    return s > (float)sobol_thresh(idx) ? 1 : 0;
}

// ---- Path A: exact int partials into workspace (no atomics) ----------------
__global__ __launch_bounds__(TPB, 8) void count_partial(const float* __restrict__ prob,
                                                        const int* __restrict__ idx,
                                                        int* __restrict__ partial) {
    const int col4 = blockIdx.x * TPB + threadIdx.x;   // float4 index within a row
    const int row0 = blockIdx.y * ROWS;
    const float4* p4 = (const float4*)prob;
    const int4*   i4 = (const int4*)idx;
    size_t v = (size_t)row0 * (F / 4) + col4;

    int c0 = 0, c1 = 0, c2 = 0, c3 = 0;
#pragma unroll 4
    for (int r = 0; r < ROWS; ++r) {
        float4 p = p4[v];
        int4   q = i4[v];
        v += F / 4;
        c0 += bitval(p.x, q.x);
        c1 += bitval(p.y, q.y);
        c2 += bitval(p.z, q.z);
        c3 += bitval(p.w, q.w);
    }
    int4 c = make_int4(c0, c1, c2, c3);
    *(int4*)&partial[(size_t)blockIdx.y * F + (size_t)col4 * 4] = c;
}

__global__ __launch_bounds__(TPB, 8) void finalize_partials(const int* __restrict__ partial,
                                                            const float* __restrict__ acc,
                                                            float* __restrict__ out) {
    // 4 columns per thread, int4 loads; lanes read consecutive int4s -> coalesced
    const int col4 = blockIdx.x * TPB + threadIdx.x;
    int4 s = make_int4(0, 0, 0, 0);
#pragma unroll 8
    for (int c = 0; c < CHUNKS; ++c) {
        int4 p = *(const int4*)&partial[(size_t)c * F + (size_t)col4 * 4];
        s.x += p.x; s.y += p.y; s.z += p.z; s.w += p.w;
    }
    const float4 a = *(const float4*)&acc[(size_t)col4 * 4];
    float4 o;
    o.x = (a.x + (float)s.x >= 4096.0f) ? 1.0f : 0.0f;
    o.y = (a.y + (float)s.y >= 4096.0f) ? 1.0f : 0.0f;
    o.z = (a.z + (float)s.z >= 4096.0f) ? 1.0f : 0.0f;
    o.w = (a.w + (float)s.w >= 4096.0f) ? 1.0f : 0.0f;
    *(float4*)&out[(size_t)col4 * 4] = o;
}

// ---- Path B (fallback if ws too small): float atomics into d_out -----------
__global__ __launch_bounds__(TPB) void zero_out(float* __restrict__ out) {
    out[blockIdx.x * TPB + threadIdx.x] = 0.0f;
}

__global__ __launch_bounds__(TPB) void count_atomic(const float* __restrict__ prob,
                                                    const int* __restrict__ idx,
                                                    float* __restrict__ out) {
    const int col4 = blockIdx.x * TPB + threadIdx.x;
    const int row0 = blockIdx.y * ROWS;
    const float4* p4 = (const float4*)prob;
    const int4*   i4 = (const int4*)idx;
    size_t v = (size_t)row0 * (F / 4) + col4;

    int c0 = 0, c1 = 0, c2 = 0, c3 = 0;
#pragma unroll 4
    for (int r = 0; r < ROWS; ++r) {
        float4 p = p4[v];
        int4   q = i4[v];
        v += F / 4;
        c0 += bitval(p.x, q.x);
        c1 += bitval(p.y, q.y);
        c2 += bitval(p.z, q.z);
        c3 += bitval(p.w, q.w);
    }
    float* o = out + (size_t)col4 * 4;
    atomicAdd(o + 0, (float)c0);
    atomicAdd(o + 1, (float)c1);
    atomicAdd(o + 2, (float)c2);
    atomicAdd(o + 3, (float)c3);
}

__global__ __launch_bounds__(TPB) void finalize_inplace(const float* __restrict__ acc,
                                                        float* __restrict__ out) {
    const int f = blockIdx.x * TPB + threadIdx.x;
    out[f] = (acc[f] + out[f] >= 4096.0f) ? 1.0f : 0.0f;
}

extern "C" void kernel_launch(void* const* d_in, const int* in_sizes, int n_in,
                              void* d_out, int out_size, void* d_ws, size_t ws_size,
                              hipStream_t stream) {
    // setup_inputs order: st_in_prob[0], accumulator[1], input_bits[2] (UNUSED), rng_idx[3]
    const float* prob = (const float*)d_in[0];
    const float* acc  = (const float*)d_in[1];
    const int*   idx  = (const int*)d_in[3];
    float* out = (float*)d_out;

    const size_t need = (size_t)CHUNKS * F * sizeof(int);   // 8 MiB
    dim3 grid(XB, CHUNKS);
    if (ws_size >= need) {
        int* partial = (int*)d_ws;
        count_partial<<<grid, TPB, 0, stream>>>(prob, idx, partial);
        finalize_partials<<<F / (TPB * 4), TPB, 0, stream>>>(partial, acc, out);
    } else {
        zero_out<<<F / TPB, TPB, 0, stream>>>(out);
        count_atomic<<<grid, TPB, 0, stream>>>(prob, idx, out);
        finalize_inplace<<<F / TPB, TPB, 0, stream>>>(acc, out);
    }
}

// Round 3
// 9.670 us; speedup vs baseline: 11.8376x; 11.3653x over previous
//
#include <hip/hip_runtime.h>

// Problem constants (fixed by the reference).
constexpr int N = 4096;      // IN_FEATURES (reduction axis)
constexpr int F = 16384;     // OUT_DIM
constexpr int TPB = 64;      // one wave per block -> __all() exit vote, no barriers
constexpr int BLOCKS = F / TPB;   // 256 blocks, 1 column per thread

// SOBOL_RNG[i] == bitreverse8(gray(i)) for BITWIDTH=8 — closed form of the
// gray-code Sobol construction (bijection of 0..255), verified vs reference.
__device__ __forceinline__ int sobol_thresh(int idx) {
    unsigned g = (unsigned)idx & 255u;   // rng_idx % 256
    g ^= g >> 1;                         // gray code
    return (int)(__brev(g) >> 24);       // 8-bit bit reversal
}

// bit = rint((p+1)*128) > SOBOL[idx]; fmaf(p,128,128) == fl(p+1)*128 exactly
// (power-of-2 scale commutes with rounding), rintf == jnp.round (half-even).
// This exact path validated absmax=0 in prior rounds.
__device__ __forceinline__ int bitval(float p, int idx) {
    float s = rintf(fmaf(p, 128.0f, 128.0f));
    return s > (float)sobol_thresh(idx) ? 1 : 0;
}

// Exact algorithm with early termination (correct for ANY inputs):
//   out[f] = (fp32(acc[f] + cnt[f]) >= 4096)  where cnt = # set bits in column f.
// Define cnt* = min integer c with fp32(acc + c) >= 4096 (monotone in c).
// Then out[f] = (cnt >= cnt*). While scanning rows:
//   sure-one  if cnt >= cnt*              (cnt only grows)
//   sure-zero if cnt + remaining < cnt*   (can't reach cnt*)
// A wave stops as soon as all 64 of its columns are decided. Worst case =
// full scan (exact); for uniform inputs cnt* = 4096 (or 4095 near the fp32
// rounding boundary) and every column is decided within ~2 zero-bits.
__global__ __launch_bounds__(TPB) void unary_scan(const float* __restrict__ prob,
                                                  const int* __restrict__ idx,
                                                  const float* __restrict__ acc,
                                                  float* __restrict__ out) {
    const int col = blockIdx.x * TPB + threadIdx.x;
    const float a = acc[col];

    // cnt*: start near 4096 - a and fix up with the exact fp32 compare.
    int cstar = 4096 - (int)a;
    if (cstar < 0) cstar = 0;
    if (cstar > N + 1) cstar = N + 1;
    while (cstar > 0 && a + (float)(cstar - 1) >= 4096.0f) --cstar;
    while (cstar <= N && a + (float)cstar < 4096.0f) ++cstar;
    // cstar in [0, N+1]; cstar == N+1 means unreachable -> out 0.

    const float* p = prob + col;
    const int*   q = idx + col;
    int cnt = 0;
    int r = 0;
    while (r < N) {
        // 32-row window, unroll for load-level parallelism
        #pragma unroll 8
        for (int k = 0; k < 32; ++k) {
            float pv = p[(size_t)(r + k) * F];
            int   qv = q[(size_t)(r + k) * F];
            cnt += bitval(pv, qv);
        }
        r += 32;
        const int remaining = N - r;
        const bool decided = (cnt >= cstar) | (cnt + remaining < cstar);
        if (__all((int)decided)) break;   // whole-wave vote, no barrier needed
    }
    out[col] = (cnt >= cstar) ? 1.0f : 0.0f;
}

extern "C" void kernel_launch(void* const* d_in, const int* in_sizes, int n_in,
                              void* d_out, int out_size, void* d_ws, size_t ws_size,
                              hipStream_t stream) {
    // setup_inputs order: st_in_prob[0], accumulator[1], input_bits[2] (UNUSED), rng_idx[3]
    const float* prob = (const float*)d_in[0];
    const float* acc  = (const float*)d_in[1];
    const int*   idx  = (const int*)d_in[3];
    float* out = (float*)d_out;

    unary_scan<<<BLOCKS, TPB, 0, stream>>>(prob, idx, acc, out);
}